// Round 6
// baseline (247.590 us; speedup 1.0000x reference)
//
#include <hip/hip_runtime.h>
#include <math.h>

using bf16x8 = __attribute__((ext_vector_type(8))) __bf16;
using bf16x2 = __attribute__((ext_vector_type(2))) __bf16;
using f32x4  = __attribute__((ext_vector_type(4))) float;

#if __has_builtin(__builtin_amdgcn_exp2f)
#define EXP2F(x) __builtin_amdgcn_exp2f(x)
#else
#define EXP2F(x) exp2f(x)
#endif

__device__ __forceinline__ unsigned short f2bf(float f) {
  unsigned u = __float_as_uint(f);
  unsigned r = u + 0x7fffu + ((u >> 16) & 1u);
  return (unsigned short)(r >> 16);
}
__device__ __forceinline__ unsigned pk_bf16(float lo, float hi) {
#if __has_builtin(__builtin_amdgcn_cvt_pk_bf16_f32)
  bf16x2 p = __builtin_amdgcn_cvt_pk_bf16_f32(lo, hi);
  return __builtin_bit_cast(unsigned, p);
#else
  return (unsigned)f2bf(lo) | ((unsigned)f2bf(hi) << 16);
#endif
}

__device__ __forceinline__ f32x4 mfma16(uint4 a, uint4 b, f32x4 c) {
  return __builtin_amdgcn_mfma_f32_16x16x32_bf16(
      __builtin_bit_cast(bf16x8, a), __builtin_bit_cast(bf16x8, b), c, 0, 0, 0);
}
__device__ __forceinline__ float swz_xor16(float v) {
  return __int_as_float(__builtin_amdgcn_ds_swizzle(__float_as_int(v), 0x401F));
}

// shared B-fragment layout (64 cols): chunk=((n>>4)*2+(k>>5))*64+((k>>3)&3)*16+(n&15)
#define FRAG_OFF(k, n) (((((n) >> 4) * 2 + ((k) >> 5)) * 64 + (((k) >> 3) & 3) * 16 + ((n) & 15)) * 8 + ((k) & 7))
// per-wave local B-fragment layout, 16 cols
#define LFRAG_OFF(k, nl) (((((k) >> 5) * 64) + ((((k) >> 3) & 3) * 16) + (nl)) * 8 + ((k) & 7))

// attention prescale: (1/sqrt(8)) * log2(e), folded into AQ/qb2
#define ATT_C 0.51006997f

// ---------------- precompute (unchanged from r5) ----------------
__global__ void precompute_kernel(
    const float* __restrict__ conv1_w, const float* __restrict__ conv2_w,
    const float* __restrict__ pm1_w, const float* __restrict__ pm1_b,
    const float* __restrict__ pm2_w,
    const float* __restrict__ q_w, const float* __restrict__ q_b,
    const float* __restrict__ k_w, const float* __restrict__ k_b,
    const float* __restrict__ v_w, const float* __restrict__ v_b,
    const float* __restrict__ in_w, const float* __restrict__ in_b,
    const float* __restrict__ mo_w, const float* __restrict__ out_w,
    const float* __restrict__ pattern, const float* __restrict__ points,
    const int* __restrict__ adjacency,
    unsigned short* __restrict__ wsb, float* __restrict__ wsf) {
  int idx = blockIdx.x * 256 + threadIdx.x;
  if (idx < 12288) {
    int t = idx >> 12, rem = idx & 4095;
    int oc = rem >> 6, c = rem & 63;
    wsb[idx] = f2bf(conv1_w[(oc * 64 + c) * 3 + t]);
  } else if (idx < 24576) {
    int i2 = idx - 12288;
    int t = i2 >> 12, rem = i2 & 4095;
    int oc = rem >> 6, ci = rem & 63;
    float v = ((ci >> 4) == (oc >> 4)) ? conv2_w[(oc * 16 + (ci & 15)) * 3 + t] : 0.0f;
    wsb[idx] = f2bf(v);
  } else if (idx < 28672) {
    int rem = idx - 24576;
    wsb[idx] = f2bf(pm1_w[(rem >> 6) * 80 + (rem & 63)]);
  } else if (idx < 32768) {
    wsb[idx] = f2bf(pm2_w[idx - 28672]);
  } else if (idx < 36864) {                // AQ = (wq @ q_w) * ATT_C
    int rem = idx - 32768; int c = rem >> 6, k = rem & 63;
    float s = 0.f;
    #pragma unroll 8
    for (int j = 0; j < 64; ++j) s += in_w[c * 64 + j] * q_w[j * 64 + k];
    wsb[idx] = f2bf(s * ATT_C);
  } else if (idx < 40960) {                // AK
    int rem = idx - 36864; int c = rem >> 6, k = rem & 63;
    float s = 0.f;
    #pragma unroll 8
    for (int j = 0; j < 64; ++j) s += in_w[(64 + c) * 64 + j] * k_w[j * 64 + k];
    wsb[idx] = f2bf(s);
  } else if (idx < 45056) {                // AV
    int rem = idx - 40960; int c = rem >> 6, k = rem & 63;
    float s = 0.f;
    #pragma unroll 8
    for (int j = 0; j < 64; ++j) s += in_w[(128 + c) * 64 + j] * v_w[j * 64 + k];
    wsb[idx] = f2bf(s);
  } else if (idx < 49152) {
    wsb[idx] = f2bf(mo_w[idx - 45056]);
  } else if (idx < 53248) {
    wsb[idx] = f2bf(out_w[idx - 49152]);
  } else if (idx < 57344) {                // CpatT[n][c]
    int rem = idx - 53248; int c = rem >> 6, n = rem & 63;
    float s = pm1_b[c];
    #pragma unroll
    for (int cp = 0; cp < 16; ++cp) s += pm1_w[c * 80 + 64 + cp] * pattern[n * 16 + cp];
    wsf[n * 64 + c] = s;
  } else if (idx < 61440) {                // geoT2[n][c]
    int rem = idx - 57344; int c = rem >> 6, n = rem & 63;
    float dd = 1e-12f;
    #pragma unroll
    for (int i = 0; i < 3; ++i) { float d = points[n * 3 + i] - points[c * 3 + i]; dd += d * d; }
    float dist = sqrtf(dd);
    wsf[4096 + n * 64 + c] = (adjacency[n * 64 + c] > 0) ? 0.5f : (-0.1f / (1.0f + dist));
  } else if (idx < 61632) {
    int rem = idx - 61440; int which = rem >> 6, c = rem & 63;
    if (which == 0) {
      float s = in_b[c];
      for (int j = 0; j < 64; ++j) s += in_w[c * 64 + j] * q_b[j];
      wsf[8192 + c] = s * ATT_C;
    } else if (which == 1) {
      float s = in_b[64 + c];
      for (int j = 0; j < 64; ++j) s += in_w[(64 + c) * 64 + j] * k_b[j];
      wsf[8256 + c] = s;
    } else {
      float s = in_b[128 + c];
      for (int j = 0; j < 64; ++j) s += in_w[(128 + c) * 64 + j] * v_b[j];
      wsf[8320 + c] = s;
    }
  }
}

// LDS 36864 B = 18432 shorts (same map as r5):
//  PW @0..9216 (wave w at w*2304: BUF0 1152 + BUF1 1152)
//  XF frag @9216 (ph0-1), overlaid by K[n][72] @9216 (ph5+)
//  GUARD @13312 (zero, ph0-2 only)
//  Y1F frag @13824 (ph1-2), overlaid by V[c][72] @13824 (ph5+)
//  KPAD = K row0 pad @9280 (zeroed in ph5, read in ph6)
#define PWSZ   2304
#define B1OFF  1152
#define XFB    9216
#define KB     9216
#define KPAD   9280
#define GUARDS 13312
#define Y1B    13824
#define VB     13824

__global__ __launch_bounds__(256, 4) void fused_kernel(
    const float* __restrict__ x,
    const unsigned short* __restrict__ wsb, const float* __restrict__ wsf,
    const float* __restrict__ conv1_b, const float* __restrict__ conv2_b,
    const float* __restrict__ pm2_b, const float* __restrict__ mo_b,
    const float* __restrict__ out_b, const float* __restrict__ ln_g,
    const float* __restrict__ ln_beta, float* __restrict__ out) {
  __shared__ __align__(16) unsigned char smem_raw[36864];
  unsigned short* S16 = reinterpret_cast<unsigned short*>(smem_raw);

  const int tid  = threadIdx.x;
  const int b    = blockIdx.x;
  const int lane = tid & 63;
  const int w    = tid >> 6;
  const int l15  = lane & 15;
  const int lq   = lane >> 4;
  const bool lq0 = (lq == 0);
  const int ng   = 16 * w + l15;
  const int PW0  = w * PWSZ;
  const int PW1  = w * PWSZ + B1OFF;
  f32x4 pfs[4];

  uint4 LA[8], LB[8];
  auto loadW = [&](uint4 R[8], const unsigned short* __restrict__ Wg) {
    #pragma unroll
    for (int ct = 0; ct < 4; ++ct) {
      R[2 * ct]     = *reinterpret_cast<const uint4*>(Wg + (ct * 16 + l15) * 64 + lq * 8);
      R[2 * ct + 1] = *reinterpret_cast<const uint4*>(Wg + (ct * 16 + l15) * 64 + 32 + lq * 8);
    }
  };
  auto gemmW = [&](const uint4 R[8], uint4 b0, uint4 b1, f32x4 acc[4]) {
    #pragma unroll
    for (int ct = 0; ct < 4; ++ct) {
      acc[ct] = mfma16(R[2 * ct], b0, acc[ct]);
      acc[ct] = mfma16(R[2 * ct + 1], b1, acc[ct]);
    }
  };
  auto convB = [&](int srcBase, int t, uint4& b0, uint4& b1) {
    int np = ng + (t - 1);
    bool ok = (unsigned)np < 64u;
    int base = srcBase + ((((np >> 4) * 2) * 64) + lq * 16 + (np & 15)) * 8;
    int A0 = ok ? base : GUARDS;
    int A1 = ok ? (base + 512) : GUARDS;
    b0 = *reinterpret_cast<const uint4*>(S16 + A0);
    b1 = *reinterpret_cast<const uint4*>(S16 + A1);
  };

  // ---------- prefetch W1_t0, then Phase 0: stage x -> XF (b128 chunk writes) ----------
  loadW(LA, wsb);
  if (tid < 8) S16[GUARDS + tid] = 0;
  {
    const float* xb = x + b * 4096;
    const int n = tid & 63;
    #pragma unroll
    for (int half = 0; half < 2; ++half) {
      int oct = (tid >> 6) + half * 4;            // k-octet 0..7
      float v[8];
      #pragma unroll
      for (int j = 0; j < 8; ++j) v[j] = xb[(oct * 8 + j) * 64 + n];
      int chunk = ((n >> 4) * 2 + (oct >> 2)) * 64 + (oct & 3) * 16 + (n & 15);
      *reinterpret_cast<uint4*>(S16 + XFB + chunk * 8) =
          make_uint4(pk_bf16(v[0], v[1]), pk_bf16(v[2], v[3]),
                     pk_bf16(v[4], v[5]), pk_bf16(v[6], v[7]));
    }
  }
  __syncthreads();   // B1

  // ---------- Phase 1: conv1 (taps pipelined LA/LB) -> Y1F shared frag ----------
  {
    f32x4 acc[4] = {};
    uint4 b0, b1;
    convB(XFB, 0, b0, b1); loadW(LB, wsb + 4096);  gemmW(LA, b0, b1, acc);
    convB(XFB, 1, b0, b1); loadW(LA, wsb + 8192);  gemmW(LB, b0, b1, acc);
    convB(XFB, 2, b0, b1); loadW(LB, wsb + 12288); gemmW(LA, b0, b1, acc);
    #pragma unroll
    for (int ct = 0; ct < 4; ++ct) {
      int k0 = ct * 16 + lq * 4;
      float4 bi = *reinterpret_cast<const float4*>(conv1_b + k0);
      *reinterpret_cast<uint2*>(S16 + Y1B + FRAG_OFF(k0, ng)) =
          make_uint2(pk_bf16(fmaxf(acc[ct][0] + bi.x, 0.f), fmaxf(acc[ct][1] + bi.y, 0.f)),
                     pk_bf16(fmaxf(acc[ct][2] + bi.z, 0.f), fmaxf(acc[ct][3] + bi.w, 0.f)));
    }
  }
  __syncthreads();   // B2

  // ---------- Phase 2: conv2 -> PIF (BUF0) ----------
  {
    f32x4 acc[4] = {};
    uint4 b0, b1;
    convB(Y1B, 0, b0, b1); loadW(LA, wsb + 16384); gemmW(LB, b0, b1, acc);
    convB(Y1B, 1, b0, b1); loadW(LB, wsb + 20480); gemmW(LA, b0, b1, acc);
    convB(Y1B, 2, b0, b1); loadW(LA, wsb + 24576); gemmW(LB, b0, b1, acc);  // next: PM1A
    #pragma unroll
    for (int ct = 0; ct < 4; ++ct) {
      int k0 = ct * 16 + lq * 4;
      float4 bi = *reinterpret_cast<const float4*>(conv2_b + k0);
      *reinterpret_cast<uint2*>(S16 + PW0 + LFRAG_OFF(k0, l15)) =
          make_uint2(pk_bf16(fmaxf(acc[ct][0] + bi.x, 0.f), fmaxf(acc[ct][1] + bi.y, 0.f)),
                     pk_bf16(fmaxf(acc[ct][2] + bi.z, 0.f), fmaxf(acc[ct][3] + bi.w, 0.f)));
    }
  }
  __syncthreads();   // B3

  // ---------- Phase 3: pm1 (LA=PM1A; prefetch PM2) -> T1F (BUF1) ----------
  {
    uint4 b0 = *reinterpret_cast<const uint4*>(S16 + PW0 + lane * 8);
    uint4 b1 = *reinterpret_cast<const uint4*>(S16 + PW0 + (64 + lane) * 8);
    loadW(LB, wsb + 28672);
    f32x4 acc[4] = {};
    gemmW(LA, b0, b1, acc);
    #pragma unroll
    for (int ct = 0; ct < 4; ++ct) {
      int k0 = ct * 16 + lq * 4;
      float4 cp = *reinterpret_cast<const float4*>(wsf + ng * 64 + k0);
      *reinterpret_cast<uint2*>(S16 + PW1 + LFRAG_OFF(k0, l15)) =
          make_uint2(pk_bf16(fmaxf(acc[ct][0] + cp.x, 0.f), fmaxf(acc[ct][1] + cp.y, 0.f)),
                     pk_bf16(fmaxf(acc[ct][2] + cp.z, 0.f), fmaxf(acc[ct][3] + cp.w, 0.f)));
    }
  }

  // ---------- Phase 4: pm2 (LB=PM2; prefetch AQ) -> PFF (BUF0) + pf regs ----------
  {
    uint4 b0 = *reinterpret_cast<const uint4*>(S16 + PW1 + lane * 8);
    uint4 b1 = *reinterpret_cast<const uint4*>(S16 + PW1 + (64 + lane) * 8);
    loadW(LA, wsb + 32768);
    f32x4 acc[4] = {};
    gemmW(LB, b0, b1, acc);
    #pragma unroll
    for (int ct = 0; ct < 4; ++ct) {
      int k0 = ct * 16 + lq * 4;
      float4 bi = *reinterpret_cast<const float4*>(pm2_b + k0);
      f32x4 v;
      #pragma unroll
      for (int r = 0; r < 4; ++r) v[r] = acc[ct][r] + (&bi.x)[r];
      pfs[ct] = v;
      *reinterpret_cast<uint2*>(S16 + PW0 + LFRAG_OFF(k0, l15)) =
          make_uint2(pk_bf16(v[0], v[1]), pk_bf16(v[2], v[3]));
    }
  }

  // ---------- Phase 5: Q/K/V (shared bq; pipelined AK/AV/MO prefetch) ----------
  uint4 qf[8];
  {
    uint4 bq0 = *reinterpret_cast<const uint4*>(S16 + PW0 + lane * 8);
    uint4 bq1 = *reinterpret_cast<const uint4*>(S16 + PW0 + (64 + lane) * 8);
    loadW(LB, wsb + 36864);                 // AK
    {
      f32x4 acc[4] = {};
      gemmW(LA, bq0, bq1, acc);             // Q
      #pragma unroll
      for (int ct = 0; ct < 4; ++ct) {
        int k0 = ct * 16 + lq * 4;
        float4 bi = *reinterpret_cast<const float4*>(wsf + 8192 + k0);
        *reinterpret_cast<uint2*>(S16 + PW1 + l15 * 72 + k0) =
            make_uint2(pk_bf16(acc[ct][0] + bi.x, acc[ct][1] + bi.y),
                       pk_bf16(acc[ct][2] + bi.z, acc[ct][3] + bi.w));
      }
      if (lane == 0) *reinterpret_cast<uint4*>(S16 + PW1 + 64) = make_uint4(0, 0, 0, 0);
      #pragma unroll
      for (int h = 0; h < 8; ++h)
        qf[h] = *reinterpret_cast<const uint4*>(S16 + (lq0 ? (PW1 + l15 * 72 + h * 8) : (PW1 + 64)));
    }
    loadW(LA, wsb + 40960);                 // AV
    {
      f32x4 acc[4] = {};
      gemmW(LB, bq0, bq1, acc);             // K
      #pragma unroll
      for (int ct = 0; ct < 4; ++ct) {
        int k0 = ct * 16 + lq * 4;
        float4 bi = *reinterpret_cast<const float4*>(wsf + 8256 + k0);
        *reinterpret_cast<uint2*>(S16 + KB + ng * 72 + k0) =
            make_uint2(pk_bf16(acc[ct][0] + bi.x, acc[ct][1] + bi.y),
                       pk_bf16(acc[ct][2] + bi.z, acc[ct][3] + bi.w));
      }
      if (tid == 0) *reinterpret_cast<uint4*>(S16 + KPAD) = make_uint4(0, 0, 0, 0);
    }
    loadW(LB, wsb + 45056);                 // MO (consumed after attention)
    {
      f32x4 acc[4] = {};
      gemmW(LA, bq0, bq1, acc);             // V -> [c][72] scatter
      #pragma unroll
      for (int ct = 0; ct < 4; ++ct) {
        int k0 = ct * 16 + lq * 4;
        float4 bi = *reinterpret_cast<const float4*>(wsf + 8320 + k0);
        #pragma unroll
        for (int r = 0; r < 4; ++r)
          S16[VB + (k0 + r) * 72 + ng] = f2bf(acc[ct][r] + (&bi.x)[r]);
      }
    }
  }
  __syncthreads();   // B4

  // ---------- Phase 6: attention (qf regs, KPAD-masked K reads) -> CTXF (BUF1) ----------
  {
    #pragma unroll
    for (int h = 0; h < 8; ++h) {
      f32x4 sc[4];
      #pragma unroll
      for (int mt = 0; mt < 4; ++mt) {
        uint4 ka = *reinterpret_cast<const uint4*>(
            S16 + (lq0 ? (KB + (mt * 16 + l15) * 72 + h * 8) : KPAD));
        f32x4 z = {0.f, 0.f, 0.f, 0.f};
        sc[mt] = mfma16(ka, qf[h], z);       // S[m][nq=l15], exp2 domain
      }
      float sum = 0.f;
      #pragma unroll
      for (int mt = 0; mt < 4; ++mt)
        #pragma unroll
        for (int r = 0; r < 4; ++r) {
          float e = EXP2F(sc[mt][r]);
          sc[mt][r] = e; sum += e;
        }
      sum += swz_xor16(sum);
      sum += __shfl_xor(sum, 32);
      float inv = __builtin_amdgcn_rcpf(sum);
      #pragma unroll
      for (int mt = 0; mt < 4; ++mt) {       // unnormalized P -> Pscr (BUF0)
        unsigned d0 = __builtin_amdgcn_perm(__float_as_uint(sc[mt][1]),
                                            __float_as_uint(sc[mt][0]), 0x07060302u);
        unsigned d1 = __builtin_amdgcn_perm(__float_as_uint(sc[mt][3]),
                                            __float_as_uint(sc[mt][2]), 0x07060302u);
        *reinterpret_cast<uint2*>(S16 + PW0 + l15 * 72 + mt * 16 + lq * 4) = make_uint2(d0, d1);
      }
      f32x4 ctx = {0.f, 0.f, 0.f, 0.f};
      #pragma unroll
      for (int ks = 0; ks < 2; ++ks) {
        uint4 pa = *reinterpret_cast<const uint4*>(S16 + PW0 + l15 * 72 + ks * 32 + lq * 8);
        uint4 vb = *reinterpret_cast<const uint4*>(S16 + VB + (h * 8 + (l15 & 7)) * 72 + ks * 32 + lq * 8);
        ctx = mfma16(pa, vb, ctx);
      }
      if (l15 < 8) {                         // ctx row nq=lq*4+r, col d=l15 -> CTXF
        int chunk = (h >> 2) * 64 + (h & 3) * 16;
        #pragma unroll
        for (int r = 0; r < 4; ++r)
          S16[PW1 + (chunk + lq * 4 + r) * 8 + l15] = f2bf(ctx[r] * inv);
      }
    }
  }

  // ---------- Phase 7: MO (LB; prefetch OUT) + mo_b + geoT2 + pf -> hv regs ----------
  f32x4 hv[4];
  {
    uint4 b0 = *reinterpret_cast<const uint4*>(S16 + PW1 + lane * 8);
    uint4 b1 = *reinterpret_cast<const uint4*>(S16 + PW1 + (64 + lane) * 8);
    loadW(LA, wsb + 49152);
    f32x4 acc[4] = {};
    gemmW(LB, b0, b1, acc);
    #pragma unroll
    for (int ct = 0; ct < 4; ++ct) {
      int k0 = ct * 16 + lq * 4;
      float4 mb = *reinterpret_cast<const float4*>(mo_b + k0);
      float4 ge = *reinterpret_cast<const float4*>(wsf + 4096 + ng * 64 + k0);
      #pragma unroll
      for (int r = 0; r < 4; ++r)
        hv[ct][r] = acc[ct][r] + (&mb.x)[r] + (&ge.x)[r] + pfs[ct][r];
    }
  }

  // ---------- Phase 8: LayerNorm (regs + shuffles) -> HNF (BUF0) ----------
  {
    float sum = 0.f, ssq = 0.f;
    #pragma unroll
    for (int ct = 0; ct < 4; ++ct)
      #pragma unroll
      for (int r = 0; r < 4; ++r) { float v = hv[ct][r]; sum += v; ssq += v * v; }
    sum += swz_xor16(sum); sum += __shfl_xor(sum, 32);
    ssq += swz_xor16(ssq); ssq += __shfl_xor(ssq, 32);
    float mu = sum * (1.0f / 64.0f);
    float var = ssq * (1.0f / 64.0f) - mu * mu;
    float rs = rsqrtf(var + 1e-5f);
    #pragma unroll
    for (int ct = 0; ct < 4; ++ct) {
      int k0 = ct * 16 + lq * 4;
      float4 g4 = *reinterpret_cast<const float4*>(ln_g + k0);
      float4 b4 = *reinterpret_cast<const float4*>(ln_beta + k0);
      float h0 = (hv[ct][0] - mu) * rs * g4.x + b4.x;
      float h1 = (hv[ct][1] - mu) * rs * g4.y + b4.y;
      float h2 = (hv[ct][2] - mu) * rs * g4.z + b4.z;
      float h3 = (hv[ct][3] - mu) * rs * g4.w + b4.w;
      *reinterpret_cast<uint2*>(S16 + PW0 + LFRAG_OFF(k0, l15)) =
          make_uint2(pk_bf16(h0, h1), pk_bf16(h2, h3));
    }
  }

  // ---------- Phase 9: OUT (LA) + out_b -> global [b][c][n] ----------
  {
    uint4 b0 = *reinterpret_cast<const uint4*>(S16 + PW0 + lane * 8);
    uint4 b1 = *reinterpret_cast<const uint4*>(S16 + PW0 + (64 + lane) * 8);
    f32x4 acc[4] = {};
    gemmW(LA, b0, b1, acc);
    float* ob = out + b * 4096;
    #pragma unroll
    for (int ct = 0; ct < 4; ++ct) {
      int k0 = ct * 16 + lq * 4;
      float4 bi = *reinterpret_cast<const float4*>(out_b + k0);
      #pragma unroll
      for (int r = 0; r < 4; ++r)
        ob[(k0 + r) * 64 + ng] = acc[ct][r] + (&bi.x)[r];
    }
  }
}

extern "C" void kernel_launch(void* const* d_in, const int* in_sizes, int n_in,
                              void* d_out, int out_size, void* d_ws, size_t ws_size,
                              hipStream_t stream) {
  const float* x        = (const float*)d_in[0];
  const float* points   = (const float*)d_in[1];
  const float* conv1_w  = (const float*)d_in[2];
  const float* conv1_b  = (const float*)d_in[3];
  const float* conv2_w  = (const float*)d_in[4];
  const float* conv2_b  = (const float*)d_in[5];
  const float* pattern  = (const float*)d_in[6];
  const float* pm1_w    = (const float*)d_in[7];
  const float* pm1_b    = (const float*)d_in[8];
  const float* pm2_w    = (const float*)d_in[9];
  const float* pm2_b    = (const float*)d_in[10];
  const float* q_w      = (const float*)d_in[11];
  const float* q_b      = (const float*)d_in[12];
  const float* k_w      = (const float*)d_in[13];
  const float* k_b      = (const float*)d_in[14];
  const float* v_w      = (const float*)d_in[15];
  const float* v_b      = (const float*)d_in[16];
  const float* in_w     = (const float*)d_in[17];
  const float* in_b     = (const float*)d_in[18];
  const float* mo_w     = (const float*)d_in[19];
  const float* mo_b     = (const float*)d_in[20];
  const float* out_w    = (const float*)d_in[21];
  const float* out_b    = (const float*)d_in[22];
  const float* ln_g     = (const float*)d_in[23];
  const float* ln_beta  = (const float*)d_in[24];
  const int*   adjacency= (const int*)d_in[25];

  unsigned short* wsb = (unsigned short*)d_ws;
  float* wsf = (float*)((char*)d_ws + 106496);

  precompute_kernel<<<241, 256, 0, stream>>>(
      conv1_w, conv2_w, pm1_w, pm1_b, pm2_w, q_w, q_b, k_w, k_b, v_w, v_b,
      in_w, in_b, mo_w, out_w, pattern, points, adjacency, wsb, wsf);

  fused_kernel<<<2048, 256, 0, stream>>>(
      x, wsb, wsf, conv1_b, conv2_b, pm2_b, mo_b, out_b, ln_g, ln_beta,
      (float*)d_out);
}

// Round 7
// 242.520 us; speedup vs baseline: 1.0209x; 1.0209x over previous
//
#include <hip/hip_runtime.h>
#include <math.h>

using bf16x8 = __attribute__((ext_vector_type(8))) __bf16;
using bf16x2 = __attribute__((ext_vector_type(2))) __bf16;
using f32x4  = __attribute__((ext_vector_type(4))) float;

#if __has_builtin(__builtin_amdgcn_exp2f)
#define EXP2F(x) __builtin_amdgcn_exp2f(x)
#else
#define EXP2F(x) exp2f(x)
#endif

__device__ __forceinline__ unsigned short f2bf(float f) {
  unsigned u = __float_as_uint(f);
  unsigned r = u + 0x7fffu + ((u >> 16) & 1u);
  return (unsigned short)(r >> 16);
}
__device__ __forceinline__ unsigned pk_bf16(float lo, float hi) {
#if __has_builtin(__builtin_amdgcn_cvt_pk_bf16_f32)
  bf16x2 p = __builtin_amdgcn_cvt_pk_bf16_f32(lo, hi);
  return __builtin_bit_cast(unsigned, p);
#else
  return (unsigned)f2bf(lo) | ((unsigned)f2bf(hi) << 16);
#endif
}

__device__ __forceinline__ f32x4 mfma16(uint4 a, uint4 b, f32x4 c) {
  return __builtin_amdgcn_mfma_f32_16x16x32_bf16(
      __builtin_bit_cast(bf16x8, a), __builtin_bit_cast(bf16x8, b), c, 0, 0, 0);
}
__device__ __forceinline__ float swz_xor16(float v) {
  return __int_as_float(__builtin_amdgcn_ds_swizzle(__float_as_int(v), 0x401F));
}

// shared B-fragment layout (64 cols): chunk=((n>>4)*2+(k>>5))*64+((k>>3)&3)*16+(n&15)
#define FRAG_OFF(k, n) (((((n) >> 4) * 2 + ((k) >> 5)) * 64 + (((k) >> 3) & 3) * 16 + ((n) & 15)) * 8 + ((k) & 7))
// per-wave local B-fragment layout, 16 cols
#define LFRAG_OFF(k, nl) (((((k) >> 5) * 64) + ((((k) >> 3) & 3) * 16) + (nl)) * 8 + ((k) & 7))

// attention prescale: (1/sqrt(8)) * log2(e), folded into AQ/qb2
#define ATT_C 0.51006997f

// ---------------- precompute (unchanged) ----------------
__global__ void precompute_kernel(
    const float* __restrict__ conv1_w, const float* __restrict__ conv2_w,
    const float* __restrict__ pm1_w, const float* __restrict__ pm1_b,
    const float* __restrict__ pm2_w,
    const float* __restrict__ q_w, const float* __restrict__ q_b,
    const float* __restrict__ k_w, const float* __restrict__ k_b,
    const float* __restrict__ v_w, const float* __restrict__ v_b,
    const float* __restrict__ in_w, const float* __restrict__ in_b,
    const float* __restrict__ mo_w, const float* __restrict__ out_w,
    const float* __restrict__ pattern, const float* __restrict__ points,
    const int* __restrict__ adjacency,
    unsigned short* __restrict__ wsb, float* __restrict__ wsf) {
  int idx = blockIdx.x * 256 + threadIdx.x;
  if (idx < 12288) {
    int t = idx >> 12, rem = idx & 4095;
    int oc = rem >> 6, c = rem & 63;
    wsb[idx] = f2bf(conv1_w[(oc * 64 + c) * 3 + t]);
  } else if (idx < 24576) {
    int i2 = idx - 12288;
    int t = i2 >> 12, rem = i2 & 4095;
    int oc = rem >> 6, ci = rem & 63;
    float v = ((ci >> 4) == (oc >> 4)) ? conv2_w[(oc * 16 + (ci & 15)) * 3 + t] : 0.0f;
    wsb[idx] = f2bf(v);
  } else if (idx < 28672) {
    int rem = idx - 24576;
    wsb[idx] = f2bf(pm1_w[(rem >> 6) * 80 + (rem & 63)]);
  } else if (idx < 32768) {
    wsb[idx] = f2bf(pm2_w[idx - 28672]);
  } else if (idx < 36864) {                // AQ = (wq @ q_w) * ATT_C
    int rem = idx - 32768; int c = rem >> 6, k = rem & 63;
    float s = 0.f;
    #pragma unroll 8
    for (int j = 0; j < 64; ++j) s += in_w[c * 64 + j] * q_w[j * 64 + k];
    wsb[idx] = f2bf(s * ATT_C);
  } else if (idx < 40960) {                // AK
    int rem = idx - 36864; int c = rem >> 6, k = rem & 63;
    float s = 0.f;
    #pragma unroll 8
    for (int j = 0; j < 64; ++j) s += in_w[(64 + c) * 64 + j] * k_w[j * 64 + k];
    wsb[idx] = f2bf(s);
  } else if (idx < 45056) {                // AV
    int rem = idx - 40960; int c = rem >> 6, k = rem & 63;
    float s = 0.f;
    #pragma unroll 8
    for (int j = 0; j < 64; ++j) s += in_w[(128 + c) * 64 + j] * v_w[j * 64 + k];
    wsb[idx] = f2bf(s);
  } else if (idx < 49152) {
    wsb[idx] = f2bf(mo_w[idx - 45056]);
  } else if (idx < 53248) {
    wsb[idx] = f2bf(out_w[idx - 49152]);
  } else if (idx < 57344) {                // CpatT[n][c]
    int rem = idx - 53248; int c = rem >> 6, n = rem & 63;
    float s = pm1_b[c];
    #pragma unroll
    for (int cp = 0; cp < 16; ++cp) s += pm1_w[c * 80 + 64 + cp] * pattern[n * 16 + cp];
    wsf[n * 64 + c] = s;
  } else if (idx < 61440) {                // geoT2[n][c]
    int rem = idx - 57344; int c = rem >> 6, n = rem & 63;
    float dd = 1e-12f;
    #pragma unroll
    for (int i = 0; i < 3; ++i) { float d = points[n * 3 + i] - points[c * 3 + i]; dd += d * d; }
    float dist = sqrtf(dd);
    wsf[4096 + n * 64 + c] = (adjacency[n * 64 + c] > 0) ? 0.5f : (-0.1f / (1.0f + dist));
  } else if (idx < 61632) {
    int rem = idx - 61440; int which = rem >> 6, c = rem & 63;
    if (which == 0) {
      float s = in_b[c];
      for (int j = 0; j < 64; ++j) s += in_w[c * 64 + j] * q_b[j];
      wsf[8192 + c] = s * ATT_C;
    } else if (which == 1) {
      float s = in_b[64 + c];
      for (int j = 0; j < 64; ++j) s += in_w[(64 + c) * 64 + j] * k_b[j];
      wsf[8256 + c] = s;
    } else {
      float s = in_b[128 + c];
      for (int j = 0; j < 64; ++j) s += in_w[(128 + c) * 64 + j] * v_b[j];
      wsf[8320 + c] = s;
    }
  }
}

// LDS 36864 B = 18432 shorts (same map as r5/r6):
//  PW @0..9216 (wave w at w*2304: BUF0 1152 + BUF1 1152)
//  XF frag @9216 (ph0-1), overlaid by K[n][72] @9216 (ph5+)
//  GUARDS @13312 (zero, ph0-2 only)
//  Y1F frag @13824 (ph1-2), overlaid by V[c][72] @13824 (ph5+)
//  KPAD = K row0 pad @9280 (zeroed in ph5, zero-source in ph6)
#define PWSZ   2304
#define B1OFF  1152
#define XFB    9216
#define KB     9216
#define KPAD   9280
#define GUARDS 13312
#define Y1B    13824
#define VB     13824

// ---- named-register weight pipeline (no arrays -> no scratch) ----
#define DECLW(P) uint4 P##0, P##1, P##2, P##3, P##4, P##5, P##6, P##7
#define LOADW(P, Wg) do { const unsigned short* _wp = (Wg);                              \
  P##0 = *reinterpret_cast<const uint4*>(_wp + (l15) * 64 + lq * 8);                     \
  P##1 = *reinterpret_cast<const uint4*>(_wp + (l15) * 64 + 32 + lq * 8);                \
  P##2 = *reinterpret_cast<const uint4*>(_wp + (16 + l15) * 64 + lq * 8);                \
  P##3 = *reinterpret_cast<const uint4*>(_wp + (16 + l15) * 64 + 32 + lq * 8);           \
  P##4 = *reinterpret_cast<const uint4*>(_wp + (32 + l15) * 64 + lq * 8);                \
  P##5 = *reinterpret_cast<const uint4*>(_wp + (32 + l15) * 64 + 32 + lq * 8);           \
  P##6 = *reinterpret_cast<const uint4*>(_wp + (48 + l15) * 64 + lq * 8);                \
  P##7 = *reinterpret_cast<const uint4*>(_wp + (48 + l15) * 64 + 32 + lq * 8); } while (0)
#define GEMMW(P, b0, b1) do {                                                            \
  acc0 = mfma16(P##0, b0, acc0); acc0 = mfma16(P##1, b1, acc0);                          \
  acc1 = mfma16(P##2, b0, acc1); acc1 = mfma16(P##3, b1, acc1);                          \
  acc2 = mfma16(P##4, b0, acc2); acc2 = mfma16(P##5, b1, acc2);                          \
  acc3 = mfma16(P##6, b0, acc3); acc3 = mfma16(P##7, b1, acc3); } while (0)
#define ZACC f32x4 acc0 = {0.f,0.f,0.f,0.f}, acc1 = acc0, acc2 = acc0, acc3 = acc0
#define CONVB(srcBase, t) do {                                                           \
  int _np = ng + ((t) - 1);                                                              \
  bool _ok = (unsigned)_np < 64u;                                                        \
  int _base = (srcBase) + ((((_np >> 4) * 2) * 64) + lq * 16 + (_np & 15)) * 8;          \
  cb0 = *reinterpret_cast<const uint4*>(S16 + (_ok ? _base : GUARDS));                   \
  cb1 = *reinterpret_cast<const uint4*>(S16 + (_ok ? (_base + 512) : GUARDS)); } while (0)

// attention per-head body (sc arrays avoided; everything named)
#define ATTH(H, QF) do {                                                                 \
  f32x4 zz = {0.f, 0.f, 0.f, 0.f};                                                      \
  uint4 ka0 = *reinterpret_cast<const uint4*>(S16 + (lq0 ? (KB + (l15) * 72 + (H) * 8) : KPAD));       \
  uint4 ka1 = *reinterpret_cast<const uint4*>(S16 + (lq0 ? (KB + (16 + l15) * 72 + (H) * 8) : KPAD));  \
  uint4 ka2 = *reinterpret_cast<const uint4*>(S16 + (lq0 ? (KB + (32 + l15) * 72 + (H) * 8) : KPAD));  \
  uint4 ka3 = *reinterpret_cast<const uint4*>(S16 + (lq0 ? (KB + (48 + l15) * 72 + (H) * 8) : KPAD));  \
  f32x4 s0 = mfma16(ka0, QF, zz), s1 = mfma16(ka1, QF, zz);                              \
  f32x4 s2 = mfma16(ka2, QF, zz), s3 = mfma16(ka3, QF, zz);                              \
  float sum = 0.f;                                                                       \
  s0[0]=EXP2F(s0[0]); sum+=s0[0]; s0[1]=EXP2F(s0[1]); sum+=s0[1];                        \
  s0[2]=EXP2F(s0[2]); sum+=s0[2]; s0[3]=EXP2F(s0[3]); sum+=s0[3];                        \
  s1[0]=EXP2F(s1[0]); sum+=s1[0]; s1[1]=EXP2F(s1[1]); sum+=s1[1];                        \
  s1[2]=EXP2F(s1[2]); sum+=s1[2]; s1[3]=EXP2F(s1[3]); sum+=s1[3];                        \
  s2[0]=EXP2F(s2[0]); sum+=s2[0]; s2[1]=EXP2F(s2[1]); sum+=s2[1];                        \
  s2[2]=EXP2F(s2[2]); sum+=s2[2]; s2[3]=EXP2F(s2[3]); sum+=s2[3];                        \
  s3[0]=EXP2F(s3[0]); sum+=s3[0]; s3[1]=EXP2F(s3[1]); sum+=s3[1];                        \
  s3[2]=EXP2F(s3[2]); sum+=s3[2]; s3[3]=EXP2F(s3[3]); sum+=s3[3];                        \
  sum += swz_xor16(sum); sum += __shfl_xor(sum, 32);                                     \
  float inv = __builtin_amdgcn_rcpf(sum);                                                \
  *reinterpret_cast<uint2*>(S16 + PW0 + l15 * 72 + 0 + lq * 4) = make_uint2(             \
      __builtin_amdgcn_perm(__float_as_uint(s0[1]), __float_as_uint(s0[0]), 0x07060302u),\
      __builtin_amdgcn_perm(__float_as_uint(s0[3]), __float_as_uint(s0[2]), 0x07060302u));\
  *reinterpret_cast<uint2*>(S16 + PW0 + l15 * 72 + 16 + lq * 4) = make_uint2(            \
      __builtin_amdgcn_perm(__float_as_uint(s1[1]), __float_as_uint(s1[0]), 0x07060302u),\
      __builtin_amdgcn_perm(__float_as_uint(s1[3]), __float_as_uint(s1[2]), 0x07060302u));\
  *reinterpret_cast<uint2*>(S16 + PW0 + l15 * 72 + 32 + lq * 4) = make_uint2(            \
      __builtin_amdgcn_perm(__float_as_uint(s2[1]), __float_as_uint(s2[0]), 0x07060302u),\
      __builtin_amdgcn_perm(__float_as_uint(s2[3]), __float_as_uint(s2[2]), 0x07060302u));\
  *reinterpret_cast<uint2*>(S16 + PW0 + l15 * 72 + 48 + lq * 4) = make_uint2(            \
      __builtin_amdgcn_perm(__float_as_uint(s3[1]), __float_as_uint(s3[0]), 0x07060302u),\
      __builtin_amdgcn_perm(__float_as_uint(s3[3]), __float_as_uint(s3[2]), 0x07060302u));\
  f32x4 ctx = zz;                                                                        \
  {                                                                                      \
    uint4 pa0 = *reinterpret_cast<const uint4*>(S16 + PW0 + l15 * 72 + lq * 8);          \
    uint4 vb0 = *reinterpret_cast<const uint4*>(S16 + VB + ((H) * 8 + (l15 & 7)) * 72 + lq * 8);        \
    ctx = mfma16(pa0, vb0, ctx);                                                         \
    uint4 pa1 = *reinterpret_cast<const uint4*>(S16 + PW0 + l15 * 72 + 32 + lq * 8);     \
    uint4 vb1 = *reinterpret_cast<const uint4*>(S16 + VB + ((H) * 8 + (l15 & 7)) * 72 + 32 + lq * 8);   \
    ctx = mfma16(pa1, vb1, ctx);                                                         \
  }                                                                                      \
  if (l15 < 8) {                                                                         \
    int _chunk = ((H) >> 2) * 64 + ((H) & 3) * 16;                                       \
    S16[PW1 + (_chunk + lq * 4 + 0) * 8 + l15] = f2bf(ctx[0] * inv);                     \
    S16[PW1 + (_chunk + lq * 4 + 1) * 8 + l15] = f2bf(ctx[1] * inv);                     \
    S16[PW1 + (_chunk + lq * 4 + 2) * 8 + l15] = f2bf(ctx[2] * inv);                     \
    S16[PW1 + (_chunk + lq * 4 + 3) * 8 + l15] = f2bf(ctx[3] * inv);                     \
  } } while (0)

__global__ __launch_bounds__(256)
__attribute__((amdgpu_waves_per_eu(4, 4)))
void fused_kernel(
    const float* __restrict__ x,
    const unsigned short* __restrict__ wsb, const float* __restrict__ wsf,
    const float* __restrict__ conv1_b, const float* __restrict__ conv2_b,
    const float* __restrict__ pm2_b, const float* __restrict__ mo_b,
    const float* __restrict__ out_b, const float* __restrict__ ln_g,
    const float* __restrict__ ln_beta, float* __restrict__ out) {
  __shared__ __align__(16) unsigned char smem_raw[36864];
  unsigned short* S16 = reinterpret_cast<unsigned short*>(smem_raw);

  const int tid  = threadIdx.x;
  const int b    = blockIdx.x;
  const int lane = tid & 63;
  const int w    = tid >> 6;
  const int l15  = lane & 15;
  const int lq   = lane >> 4;
  const bool lq0 = (lq == 0);
  const int ng   = 16 * w + l15;
  const int PW0  = w * PWSZ;
  const int PW1  = w * PWSZ + B1OFF;
  f32x4 pf0, pf1, pf2, pf3;
  DECLW(LA);
  DECLW(LB);

  // ---------- prefetch W1_t0, then Phase 0: stage x -> XF (b128 chunk writes) ----------
  LOADW(LA, wsb);
  if (tid < 8) S16[GUARDS + tid] = 0;
  {
    const float* xb = x + b * 4096;
    const int n = tid & 63;
    #pragma unroll
    for (int half = 0; half < 2; ++half) {
      int oct = (tid >> 6) + half * 4;            // k-octet 0..7
      float v[8];
      #pragma unroll
      for (int j = 0; j < 8; ++j) v[j] = xb[(oct * 8 + j) * 64 + n];
      int chunk = ((n >> 4) * 2 + (oct >> 2)) * 64 + (oct & 3) * 16 + (n & 15);
      *reinterpret_cast<uint4*>(S16 + XFB + chunk * 8) =
          make_uint4(pk_bf16(v[0], v[1]), pk_bf16(v[2], v[3]),
                     pk_bf16(v[4], v[5]), pk_bf16(v[6], v[7]));
    }
  }
  __syncthreads();   // B1

  // ---------- Phase 1: conv1 (pipelined LA/LB) -> Y1F shared frag ----------
  {
    ZACC;
    uint4 cb0, cb1;
    CONVB(XFB, 0); LOADW(LB, wsb + 4096);  GEMMW(LA, cb0, cb1);
    CONVB(XFB, 1); LOADW(LA, wsb + 8192);  GEMMW(LB, cb0, cb1);
    CONVB(XFB, 2); LOADW(LB, wsb + 12288); GEMMW(LA, cb0, cb1);
    f32x4 acc[4] = {acc0, acc1, acc2, acc3};
    #pragma unroll
    for (int ct = 0; ct < 4; ++ct) {
      int k0 = ct * 16 + lq * 4;
      float4 bi = *reinterpret_cast<const float4*>(conv1_b + k0);
      *reinterpret_cast<uint2*>(S16 + Y1B + FRAG_OFF(k0, ng)) =
          make_uint2(pk_bf16(fmaxf(acc[ct][0] + bi.x, 0.f), fmaxf(acc[ct][1] + bi.y, 0.f)),
                     pk_bf16(fmaxf(acc[ct][2] + bi.z, 0.f), fmaxf(acc[ct][3] + bi.w, 0.f)));
    }
  }
  __syncthreads();   // B2

  // ---------- Phase 2: conv2 -> PIF (BUF0) ----------
  {
    ZACC;
    uint4 cb0, cb1;
    CONVB(Y1B, 0); LOADW(LA, wsb + 16384); GEMMW(LB, cb0, cb1);
    CONVB(Y1B, 1); LOADW(LB, wsb + 20480); GEMMW(LA, cb0, cb1);
    CONVB(Y1B, 2); LOADW(LA, wsb + 24576); GEMMW(LB, cb0, cb1);  // next: PM1A
    f32x4 acc[4] = {acc0, acc1, acc2, acc3};
    #pragma unroll
    for (int ct = 0; ct < 4; ++ct) {
      int k0 = ct * 16 + lq * 4;
      float4 bi = *reinterpret_cast<const float4*>(conv2_b + k0);
      *reinterpret_cast<uint2*>(S16 + PW0 + LFRAG_OFF(k0, l15)) =
          make_uint2(pk_bf16(fmaxf(acc[ct][0] + bi.x, 0.f), fmaxf(acc[ct][1] + bi.y, 0.f)),
                     pk_bf16(fmaxf(acc[ct][2] + bi.z, 0.f), fmaxf(acc[ct][3] + bi.w, 0.f)));
    }
  }
  __syncthreads();   // B3

  // ---------- Phase 3: pm1 (LA=PM1A; prefetch PM2) -> T1F (BUF1) ----------
  {
    uint4 b0 = *reinterpret_cast<const uint4*>(S16 + PW0 + lane * 8);
    uint4 b1 = *reinterpret_cast<const uint4*>(S16 + PW0 + (64 + lane) * 8);
    LOADW(LB, wsb + 28672);
    ZACC;
    GEMMW(LA, b0, b1);
    f32x4 acc[4] = {acc0, acc1, acc2, acc3};
    #pragma unroll
    for (int ct = 0; ct < 4; ++ct) {
      int k0 = ct * 16 + lq * 4;
      float4 cp = *reinterpret_cast<const float4*>(wsf + ng * 64 + k0);
      *reinterpret_cast<uint2*>(S16 + PW1 + LFRAG_OFF(k0, l15)) =
          make_uint2(pk_bf16(fmaxf(acc[ct][0] + cp.x, 0.f), fmaxf(acc[ct][1] + cp.y, 0.f)),
                     pk_bf16(fmaxf(acc[ct][2] + cp.z, 0.f), fmaxf(acc[ct][3] + cp.w, 0.f)));
    }
  }

  // ---------- Phase 4: pm2 (LB=PM2; prefetch AQ) -> PFF (BUF0) + pf regs ----------
  {
    uint4 b0 = *reinterpret_cast<const uint4*>(S16 + PW1 + lane * 8);
    uint4 b1 = *reinterpret_cast<const uint4*>(S16 + PW1 + (64 + lane) * 8);
    LOADW(LA, wsb + 32768);
    ZACC;
    GEMMW(LB, b0, b1);
    float4 bi0 = *reinterpret_cast<const float4*>(pm2_b + lq * 4);
    float4 bi1 = *reinterpret_cast<const float4*>(pm2_b + 16 + lq * 4);
    float4 bi2 = *reinterpret_cast<const float4*>(pm2_b + 32 + lq * 4);
    float4 bi3 = *reinterpret_cast<const float4*>(pm2_b + 48 + lq * 4);
    pf0[0]=acc0[0]+bi0.x; pf0[1]=acc0[1]+bi0.y; pf0[2]=acc0[2]+bi0.z; pf0[3]=acc0[3]+bi0.w;
    pf1[0]=acc1[0]+bi1.x; pf1[1]=acc1[1]+bi1.y; pf1[2]=acc1[2]+bi1.z; pf1[3]=acc1[3]+bi1.w;
    pf2[0]=acc2[0]+bi2.x; pf2[1]=acc2[1]+bi2.y; pf2[2]=acc2[2]+bi2.z; pf2[3]=acc2[3]+bi2.w;
    pf3[0]=acc3[0]+bi3.x; pf3[1]=acc3[1]+bi3.y; pf3[2]=acc3[2]+bi3.z; pf3[3]=acc3[3]+bi3.w;
    *reinterpret_cast<uint2*>(S16 + PW0 + LFRAG_OFF(lq * 4, l15)) =
        make_uint2(pk_bf16(pf0[0], pf0[1]), pk_bf16(pf0[2], pf0[3]));
    *reinterpret_cast<uint2*>(S16 + PW0 + LFRAG_OFF(16 + lq * 4, l15)) =
        make_uint2(pk_bf16(pf1[0], pf1[1]), pk_bf16(pf1[2], pf1[3]));
    *reinterpret_cast<uint2*>(S16 + PW0 + LFRAG_OFF(32 + lq * 4, l15)) =
        make_uint2(pk_bf16(pf2[0], pf2[1]), pk_bf16(pf2[2], pf2[3]));
    *reinterpret_cast<uint2*>(S16 + PW0 + LFRAG_OFF(48 + lq * 4, l15)) =
        make_uint2(pk_bf16(pf3[0], pf3[1]), pk_bf16(pf3[2], pf3[3]));
  }

  // ---------- Phase 5: Q -> BUF1; K -> KB; V -> VB (pipelined AK/AV) ----------
  {
    uint4 bq0 = *reinterpret_cast<const uint4*>(S16 + PW0 + lane * 8);
    uint4 bq1 = *reinterpret_cast<const uint4*>(S16 + PW0 + (64 + lane) * 8);
    LOADW(LB, wsb + 36864);                 // AK
    {
      ZACC;
      GEMMW(LA, bq0, bq1);                  // Q
      f32x4 acc[4] = {acc0, acc1, acc2, acc3};
      #pragma unroll
      for (int ct = 0; ct < 4; ++ct) {
        int k0 = ct * 16 + lq * 4;
        float4 bi = *reinterpret_cast<const float4*>(wsf + 8192 + k0);
        *reinterpret_cast<uint2*>(S16 + PW1 + l15 * 72 + k0) =
            make_uint2(pk_bf16(acc[ct][0] + bi.x, acc[ct][1] + bi.y),
                       pk_bf16(acc[ct][2] + bi.z, acc[ct][3] + bi.w));
      }
      if (lane == 0) *reinterpret_cast<uint4*>(S16 + PW1 + 64) = make_uint4(0, 0, 0, 0);
    }
    LOADW(LA, wsb + 40960);                 // AV
    {
      ZACC;
      GEMMW(LB, bq0, bq1);                  // K
      f32x4 acc[4] = {acc0, acc1, acc2, acc3};
      #pragma unroll
      for (int ct = 0; ct < 4; ++ct) {
        int k0 = ct * 16 + lq * 4;
        float4 bi = *reinterpret_cast<const float4*>(wsf + 8256 + k0);
        *reinterpret_cast<uint2*>(S16 + KB + ng * 72 + k0) =
            make_uint2(pk_bf16(acc[ct][0] + bi.x, acc[ct][1] + bi.y),
                       pk_bf16(acc[ct][2] + bi.z, acc[ct][3] + bi.w));
      }
      if (tid == 0) *reinterpret_cast<uint4*>(S16 + KPAD) = make_uint4(0, 0, 0, 0);
    }
    {
      ZACC;
      GEMMW(LA, bq0, bq1);                  // V -> [c][72] scatter
      f32x4 acc[4] = {acc0, acc1, acc2, acc3};
      #pragma unroll
      for (int ct = 0; ct < 4; ++ct) {
        int k0 = ct * 16 + lq * 4;
        float4 bi = *reinterpret_cast<const float4*>(wsf + 8320 + k0);
        #pragma unroll
        for (int r = 0; r < 4; ++r)
          S16[VB + (k0 + r) * 72 + ng] = f2bf(acc[ct][r] + (&bi.x)[r]);
      }
    }
  }
  __syncthreads();   // B4

  // ---------- Phase 6: attention (qf regs; MO prefetch covered by 8 heads) ----------
  {
    LOADW(LB, wsb + 45056);                 // MO, consumed in phase 7
    uint4 qf0, qf1, qf2, qf3, qf4, qf5, qf6, qf7;
    qf0 = *reinterpret_cast<const uint4*>(S16 + (lq0 ? (PW1 + l15 * 72 + 0)  : (PW1 + 64)));
    qf1 = *reinterpret_cast<const uint4*>(S16 + (lq0 ? (PW1 + l15 * 72 + 8)  : (PW1 + 64)));
    qf2 = *reinterpret_cast<const uint4*>(S16 + (lq0 ? (PW1 + l15 * 72 + 16) : (PW1 + 64)));
    qf3 = *reinterpret_cast<const uint4*>(S16 + (lq0 ? (PW1 + l15 * 72 + 24) : (PW1 + 64)));
    qf4 = *reinterpret_cast<const uint4*>(S16 + (lq0 ? (PW1 + l15 * 72 + 32) : (PW1 + 64)));
    qf5 = *reinterpret_cast<const uint4*>(S16 + (lq0 ? (PW1 + l15 * 72 + 40) : (PW1 + 64)));
    qf6 = *reinterpret_cast<const uint4*>(S16 + (lq0 ? (PW1 + l15 * 72 + 48) : (PW1 + 64)));
    qf7 = *reinterpret_cast<const uint4*>(S16 + (lq0 ? (PW1 + l15 * 72 + 56) : (PW1 + 64)));
    ATTH(0, qf0); ATTH(1, qf1); ATTH(2, qf2); ATTH(3, qf3);
    ATTH(4, qf4); ATTH(5, qf5); ATTH(6, qf6); ATTH(7, qf7);
  }

  // ---------- Phase 7: MO (LB; prefetch OUT) + mo_b + geoT2 + pf -> hv ----------
  f32x4 hv0, hv1, hv2, hv3;
  {
    uint4 b0 = *reinterpret_cast<const uint4*>(S16 + PW1 + lane * 8);
    uint4 b1 = *reinterpret_cast<const uint4*>(S16 + PW1 + (64 + lane) * 8);
    LOADW(LA, wsb + 49152);
    ZACC;
    GEMMW(LB, b0, b1);
    float4 mb0 = *reinterpret_cast<const float4*>(mo_b + lq * 4);
    float4 mb1 = *reinterpret_cast<const float4*>(mo_b + 16 + lq * 4);
    float4 mb2 = *reinterpret_cast<const float4*>(mo_b + 32 + lq * 4);
    float4 mb3 = *reinterpret_cast<const float4*>(mo_b + 48 + lq * 4);
    float4 ge0 = *reinterpret_cast<const float4*>(wsf + 4096 + ng * 64 + lq * 4);
    float4 ge1 = *reinterpret_cast<const float4*>(wsf + 4096 + ng * 64 + 16 + lq * 4);
    float4 ge2 = *reinterpret_cast<const float4*>(wsf + 4096 + ng * 64 + 32 + lq * 4);
    float4 ge3 = *reinterpret_cast<const float4*>(wsf + 4096 + ng * 64 + 48 + lq * 4);
    hv0[0]=acc0[0]+mb0.x+ge0.x+pf0[0]; hv0[1]=acc0[1]+mb0.y+ge0.y+pf0[1];
    hv0[2]=acc0[2]+mb0.z+ge0.z+pf0[2]; hv0[3]=acc0[3]+mb0.w+ge0.w+pf0[3];
    hv1[0]=acc1[0]+mb1.x+ge1.x+pf1[0]; hv1[1]=acc1[1]+mb1.y+ge1.y+pf1[1];
    hv1[2]=acc1[2]+mb1.z+ge1.z+pf1[2]; hv1[3]=acc1[3]+mb1.w+ge1.w+pf1[3];
    hv2[0]=acc2[0]+mb2.x+ge2.x+pf2[0]; hv2[1]=acc2[1]+mb2.y+ge2.y+pf2[1];
    hv2[2]=acc2[2]+mb2.z+ge2.z+pf2[2]; hv2[3]=acc2[3]+mb2.w+ge2.w+pf2[3];
    hv3[0]=acc3[0]+mb3.x+ge3.x+pf3[0]; hv3[1]=acc3[1]+mb3.y+ge3.y+pf3[1];
    hv3[2]=acc3[2]+mb3.z+ge3.z+pf3[2]; hv3[3]=acc3[3]+mb3.w+ge3.w+pf3[3];
  }

  // ---------- Phase 8: LayerNorm (regs + shuffles) -> HNF (BUF0) ----------
  {
    float sum = 0.f, ssq = 0.f;
    #pragma unroll
    for (int r = 0; r < 4; ++r) {
      sum += hv0[r] + hv1[r] + hv2[r] + hv3[r];
      ssq += hv0[r]*hv0[r] + hv1[r]*hv1[r] + hv2[r]*hv2[r] + hv3[r]*hv3[r];
    }
    sum += swz_xor16(sum); sum += __shfl_xor(sum, 32);
    ssq += swz_xor16(ssq); ssq += __shfl_xor(ssq, 32);
    float mu = sum * (1.0f / 64.0f);
    float var = ssq * (1.0f / 64.0f) - mu * mu;
    float rs = rsqrtf(var + 1e-5f);
    f32x4 hva[4] = {hv0, hv1, hv2, hv3};
    #pragma unroll
    for (int ct = 0; ct < 4; ++ct) {
      int k0 = ct * 16 + lq * 4;
      float4 g4 = *reinterpret_cast<const float4*>(ln_g + k0);
      float4 b4 = *reinterpret_cast<const float4*>(ln_beta + k0);
      float h0 = (hva[ct][0] - mu) * rs * g4.x + b4.x;
      float h1 = (hva[ct][1] - mu) * rs * g4.y + b4.y;
      float h2 = (hva[ct][2] - mu) * rs * g4.z + b4.z;
      float h3 = (hva[ct][3] - mu) * rs * g4.w + b4.w;
      *reinterpret_cast<uint2*>(S16 + PW0 + LFRAG_OFF(k0, l15)) =
          make_uint2(pk_bf16(h0, h1), pk_bf16(h2, h3));
    }
  }

  // ---------- Phase 9: OUT (LA) + out_b -> global [b][c][n] ----------
  {
    uint4 b0 = *reinterpret_cast<const uint4*>(S16 + PW0 + lane * 8);
    uint4 b1 = *reinterpret_cast<const uint4*>(S16 + PW0 + (64 + lane) * 8);
    ZACC;
    GEMMW(LA, b0, b1);
    f32x4 acc[4] = {acc0, acc1, acc2, acc3};
    float* ob = out + b * 4096;
    #pragma unroll
    for (int ct = 0; ct < 4; ++ct) {
      int k0 = ct * 16 + lq * 4;
      float4 bi = *reinterpret_cast<const float4*>(out_b + k0);
      #pragma unroll
      for (int r = 0; r < 4; ++r)
        ob[(k0 + r) * 64 + ng] = acc[ct][r] + (&bi.x)[r];
    }
  }
}

extern "C" void kernel_launch(void* const* d_in, const int* in_sizes, int n_in,
                              void* d_out, int out_size, void* d_ws, size_t ws_size,
                              hipStream_t stream) {
  const float* x        = (const float*)d_in[0];
  const float* points   = (const float*)d_in[1];
  const float* conv1_w  = (const float*)d_in[2];
  const float* conv1_b  = (const float*)d_in[3];
  const float* conv2_w  = (const float*)d_in[4];
  const float* conv2_b  = (const float*)d_in[5];
  const float* pattern  = (const float*)d_in[6];
  const float* pm1_w    = (const float*)d_in[7];
  const float* pm1_b    = (const float*)d_in[8];
  const float* pm2_w    = (const float*)d_in[9];
  const float* pm2_b    = (const float*)d_in[10];
  const float* q_w      = (const float*)d_in[11];
  const float* q_b      = (const float*)d_in[12];
  const float* k_w      = (const float*)d_in[13];
  const float* k_b      = (const float*)d_in[14];
  const float* v_w      = (const float*)d_in[15];
  const float* v_b      = (const float*)d_in[16];
  const float* in_w     = (const float*)d_in[17];
  const float* in_b     = (const float*)d_in[18];
  const float* mo_w     = (const float*)d_in[19];
  const float* mo_b     = (const float*)d_in[20];
  const float* out_w    = (const float*)d_in[21];
  const float* out_b    = (const float*)d_in[22];
  const float* ln_g     = (const float*)d_in[23];
  const float* ln_beta  = (const float*)d_in[24];
  const int*   adjacency= (const int*)d_in[25];

  unsigned short* wsb = (unsigned short*)d_ws;
  float* wsf = (float*)((char*)d_ws + 106496);

  precompute_kernel<<<241, 256, 0, stream>>>(
      conv1_w, conv2_w, pm1_w, pm1_b, pm2_w, q_w, q_b, k_w, k_b, v_w, v_b,
      in_w, in_b, mo_w, out_w, pattern, points, adjacency, wsb, wsf);

  fused_kernel<<<2048, 256, 0, stream>>>(
      x, wsb, wsf, conv1_b, conv2_b, pm2_b, mo_b, out_b, ln_g, ln_beta,
      (float*)d_out);
}